// Round 9
// baseline (538.170 us; speedup 1.0000x reference)
//
#include <hip/hip_runtime.h>
#include <cstdint>

// ---------------------------------------------------------------------------
// InvariantPointAttention fused kernel set for MI355X (gfx950)
// N=768, C_S=384, C_Z=128, C_IPA=16, H=12, NQ=4, NV=8
// ---------------------------------------------------------------------------

typedef __attribute__((ext_vector_type(8))) short short8;
typedef __attribute__((ext_vector_type(4))) short short4_t;
typedef __attribute__((ext_vector_type(4))) float f32x4;

__device__ __forceinline__ unsigned short f2bf(float f) {
    unsigned u = __float_as_uint(f);
    u = (u + 0x7FFFu + ((u >> 16) & 1u)) >> 16;   // RNE
    return (unsigned short)u;
}
__device__ __forceinline__ float bf2f(unsigned short s) {
    return __uint_as_float(((unsigned)s) << 16);
}
__device__ __forceinline__ unsigned pk2(float lo, float hi) {
    return (unsigned)f2bf(lo) | ((unsigned)f2bf(hi) << 16);
}
// subtile placement offset: H[g] = 6g; 44*6g mod 32 = {0,8,16,24};
// placed ranges [22g, 22g+16) are disjoint -> phase-C groups get disjoint
// 8-bank windows (2 lanes/bank = free).
__device__ __forceinline__ int HOFF(int gg) { return gg * 6; }

#define NS_QK  0.14433756729740643f   // sqrt(1/48)
#define NS_B   0.5773502691896258f    // sqrt(1/3)
#define NS_HW  0.13608276348795434f   // sqrt(1/54)

// ---------------------------------------------------------------------------
// Kernel 1: fused projection GEMM.  s (768x384) @ [Wq|Wkv|Wq3|Wkv3] (384x1152)
// ---------------------------------------------------------------------------
__global__ __launch_bounds__(256) void proj_kernel(
    const float* __restrict__ s,
    const float* __restrict__ Wq,   const float* __restrict__ bq,
    const float* __restrict__ Wkv,  const float* __restrict__ bkv,
    const float* __restrict__ Wq3,  const float* __restrict__ bq3,
    const float* __restrict__ Wkv3, const float* __restrict__ bkv3,
    float* __restrict__ Qw, unsigned short* __restrict__ Kw,
    unsigned short* __restrict__ Vt,
    float* __restrict__ P3q, float* __restrict__ P3kv)
{
    __shared__ __align__(16) float s_lds[32 * 384];
    const int t  = threadIdx.x;
    const int r0 = blockIdx.x * 32;
    const int c0 = blockIdx.y * 128;

    for (int u = t; u < 3072; u += 256) {
        int r = u / 96, c4 = u - r * 96;
        *(float4*)&s_lds[r * 384 + c4 * 4] =
            *(const float4*)&s[(size_t)(r0 + r) * 384 + c4 * 4];
    }
    __syncthreads();

    const int rg = t >> 6;
    const int lc = t & 63;
    const int colA = c0 + lc;
    const int colB = c0 + lc + 64;

    const float *wpA, *wpB; int ldA, ldB; float biasA, biasB;
    {
        int col = colA;
        if (col < 192)      { wpA = Wq   + col;       ldA = 192; biasA = bq[col]; }
        else if (col < 576) { wpA = Wkv  + (col-192); ldA = 384; biasA = bkv[col-192]; }
        else if (col < 720) { wpA = Wq3  + (col-576); ldA = 144; biasA = bq3[col-576]; }
        else                { wpA = Wkv3 + (col-720); ldA = 432; biasA = bkv3[col-720]; }
        col = colB;
        if (col < 192)      { wpB = Wq   + col;       ldB = 192; biasB = bq[col]; }
        else if (col < 576) { wpB = Wkv  + (col-192); ldB = 384; biasB = bkv[col-192]; }
        else if (col < 720) { wpB = Wq3  + (col-576); ldB = 144; biasB = bq3[col-576]; }
        else                { wpB = Wkv3 + (col-720); ldB = 432; biasB = bkv3[col-720]; }
    }

    float acc0[8] = {}, acc1[8] = {};
    for (int k = 0; k < 384; k += 4) {
        float4 sv[8];
        #pragma unroll
        for (int r = 0; r < 8; r++)
            sv[r] = *(const float4*)&s_lds[(rg*8 + r) * 384 + k];
        #pragma unroll
        for (int kk = 0; kk < 4; kk++) {
            float w0 = wpA[(k + kk) * ldA];
            float w1 = wpB[(k + kk) * ldB];
            #pragma unroll
            for (int r = 0; r < 8; r++) {
                float sval = ((const float*)&sv[r])[kk];
                acc0[r] += sval * w0;
                acc1[r] += sval * w1;
            }
        }
    }

    #pragma unroll
    for (int q = 0; q < 2; q++) {
        int col   = q ? colB : colA;
        float bia = q ? biasB : biasA;
        #pragma unroll
        for (int r = 0; r < 8; r++) {
            int row = r0 + rg*8 + r;
            float v = (q ? acc1[r] : acc0[r]) + bia;
            if (col < 192) {
                Qw[(size_t)row*192 + col] = v;
            } else if (col < 576) {
                int c = col - 192, h = c >> 5, sub = c & 31;
                if (sub < 16) Kw[(size_t)row*192 + h*16 + sub] = f2bf(v);
                else          Vt[(size_t)(h*16 + (sub-16))*768 + row] = f2bf(v);
            } else if (col < 720) {
                P3q[(size_t)row*144 + (col-576)] = v;
            } else {
                P3kv[(size_t)row*432 + (col-720)] = v;
            }
        }
    }
}

// ---------------------------------------------------------------------------
// Kernel 2: rotate/translate projected points.
// ---------------------------------------------------------------------------
__global__ __launch_bounds__(192) void rot3_kernel(
    const float* __restrict__ P3q, const float* __restrict__ P3kv,
    const float* __restrict__ rots, const float* __restrict__ trans,
    float* __restrict__ Q3w, float* __restrict__ K3w,
    unsigned short* __restrict__ V3t)
{
    const int n = blockIdx.x;
    const int t = threadIdx.x;
    float R[9];
    #pragma unroll
    for (int u = 0; u < 9; u++) R[u] = rots[n*9 + u];
    float T0 = trans[n*3+0], T1 = trans[n*3+1], T2 = trans[n*3+2];

    float p0, p1, p2;
    if (t < 48) {
        p0 = P3q[(size_t)n*144 + t];
        p1 = P3q[(size_t)n*144 + 48 + t];
        p2 = P3q[(size_t)n*144 + 96 + t];
    } else {
        int k = t - 48;
        p0 = P3kv[(size_t)n*432 + k];
        p1 = P3kv[(size_t)n*432 + 144 + k];
        p2 = P3kv[(size_t)n*432 + 288 + k];
    }
    float o0 = R[0]*p0 + R[1]*p1 + R[2]*p2 + T0;
    float o1 = R[3]*p0 + R[4]*p1 + R[5]*p2 + T1;
    float o2 = R[6]*p0 + R[7]*p1 + R[8]*p2 + T2;

    if (t < 48) {
        Q3w[(size_t)n*144 + t*3 + 0] = o0;
        Q3w[(size_t)n*144 + t*3 + 1] = o1;
        Q3w[(size_t)n*144 + t*3 + 2] = o2;
    } else {
        int k = t - 48, h = k / 12, m = k % 12;
        if (m < 4) {
            size_t base = (size_t)n*144 + (h*4 + m)*3;
            K3w[base+0] = o0; K3w[base+1] = o1; K3w[base+2] = o2;
        } else {
            int rv = (h*8 + (m-4))*3;
            V3t[(size_t)(rv+0)*768 + n] = f2bf(o0);
            V3t[(size_t)(rv+1)*768 + n] = f2bf(o1);
            V3t[(size_t)(rv+2)*768 + n] = f2bf(o2);
        }
    }
}

// ---------------------------------------------------------------------------
// Kernel 2b: build extended logit vectors (cols 30/31 = isolated mask pair).
// ---------------------------------------------------------------------------
__global__ __launch_bounds__(256) void ek_kernel(
    const float* __restrict__ Qw, const unsigned short* __restrict__ Kw,
    const float* __restrict__ Q3w, const float* __restrict__ K3w,
    const float* __restrict__ mask, const float* __restrict__ hw,
    const float* __restrict__ bb,
    unsigned short* __restrict__ EQw, unsigned short* __restrict__ EKw)
{
    const int idx = blockIdx.x * 4 + (threadIdx.x >> 6);
    const int h   = threadIdx.x & 63;
    if (h >= 12) return;
    const float hws = log1pf(__expf(hw[h])) * NS_HW;
    const float mi  = mask[idx];
    const float S   = 31616.0f;   // bf16-exact; S^2 exact in f32

    unsigned short row[32];
    // EK
    {
        const unsigned short* kp = Kw + (size_t)idx*192 + h*16;
        #pragma unroll
        for (int c = 0; c < 16; c++) row[c] = kp[c];
        const float* k3 = K3w + (size_t)idx*144 + h*12;
        float kn = 0.0f;
        #pragma unroll
        for (int e = 0; e < 12; e++) {
            unsigned short b = f2bf(k3[e]);
            row[16+e] = b;
            float f = bf2f(b); kn += f*f;
        }
        row[28] = f2bf(bb[h]*NS_B - 0.5f*hws*kn);
        row[29] = f2bf(1.0f);
        row[30] = f2bf(mi * S);
        row[31] = f2bf(-S);
        unsigned short* o = EKw + ((size_t)idx*12 + h)*32;
        #pragma unroll
        for (int c = 0; c < 32; c++) o[c] = row[c];
    }
    // EQ
    {
        const float* qp = Qw + (size_t)idx*192 + h*16;
        #pragma unroll
        for (int c = 0; c < 16; c++) row[c] = f2bf(qp[c] * NS_QK);
        const float* q3 = Q3w + (size_t)idx*144 + h*12;
        float qn = 0.0f;
        #pragma unroll
        for (int e = 0; e < 12; e++) {
            float f = q3[e];
            row[16+e] = f2bf(f * hws);
            qn += f*f;
        }
        row[28] = f2bf(1.0f);
        row[29] = f2bf(-0.5f*hws*qn);
        row[30] = f2bf(mi * S);
        row[31] = f2bf(S);
        unsigned short* o = EQw + ((size_t)idx*12 + h)*32;
        #pragma unroll
        for (int c = 0; c < 32; c++) o[c] = row[c];
    }
}

// ---------------------------------------------------------------------------
// Kernel 3: fused IPA attention — all-thread phases, in-phase z staging,
// EK-fused logits, placed z subtiles (H=6g), transposed V loads.
// Per tile: A(stage z) |bar| B1(W01 zB MFMA) |bar| B2(EK dots) |bar|
//           C(Opair MFMA + V tasks + den) |bar|
// Partial layout per block (stride 2560 f32):
//   [0:192) O rows | [192:480) O3 rows | [768:2304) Opair | [2304:2316) den
// ---------------------------------------------------------------------------
__global__ __launch_bounds__(256, 5) void ipa_main(
    const float* __restrict__ z,
    const float* __restrict__ Wb,
    const unsigned short* __restrict__ EQw, const unsigned short* __restrict__ EKw,
    const unsigned short* __restrict__ Vt, const unsigned short* __restrict__ V3t,
    float* __restrict__ part3)
{
    __shared__ __align__(16) unsigned short z_l[82 * 88];      // 14.4 KB
    __shared__ __align__(16) float          p_l[32 * 17];      // 2.2 KB
    __shared__ __align__(16) unsigned short pT_l[16 * 40];     // 1.3 KB
    __shared__ __align__(16) float          zb_l[32 * 13];     // 1.7 KB
    __shared__ __align__(16) float          eq_l[12 * 33];     // 1.6 KB
    __shared__ __align__(16) unsigned short wbT_l[16 * 136];   // 4.3 KB

    const int i     = blockIdx.x >> 1;
    const int chunk = blockIdx.x & 1;
    const int t    = threadIdx.x;
    const int lane = t & 63;
    const int wv   = t >> 6;
    const int g    = lane >> 4;
    const int lm   = lane & 15;

    // ------- init -------
    for (int u = t; u < 384; u += 256) {
        int h = u >> 5, c = u & 31;
        eq_l[h*33 + c] = bf2f(EQw[((size_t)i*12 + h)*32 + c]);
    }
    for (int u = t; u < 1536; u += 256) {
        int h = u % 12, c = u / 12;
        wbT_l[h*136 + c] = f2bf(Wb[c*12 + h]);
    }
    for (int u = t; u < 512; u += 256)
        wbT_l[(12 + (u >> 7))*136 + (u & 127)] = 0;
    if (t < 160) pT_l[480 + t] = 0;

    // stage mapping (placed subtiles, stride 88 elems)
    const int jj  = t >> 3, c16 = t & 7;
    const float* zbase = z + ((size_t)i*768 + chunk*384 + jj)*128 + c16*16;
    const int chS  = (jj >> 2)*8 + c16;
    const int chP  = chS + HOFF(chS >> 4);
    const int sidx = chP*88 + (jj & 3)*16;

    // V-row task setup
    const unsigned short* rp1 = (t < 192)
        ? Vt + (size_t)t*768 : V3t + (size_t)(t - 192)*768;
    const int h1 = (t < 192) ? (t >> 4) : ((t - 192) / 24);
    const bool has2 = (t < 224);
    const unsigned short* rp2 = V3t + (size_t)(t + 64)*768;
    const int h2 = (t + 64) / 24;
    const int denh = (t >= 224 && t < 236) ? (t - 224) : -1;

    // accumulators
    f32x4 opA = {0,0,0,0}, opB = {0,0,0,0};
    float acc1 = 0, acc2 = 0, dn = 0;

    __syncthreads();

    // ------- main loop -------
    for (int tile = 0; tile < 12; tile++) {
        const int j0 = chunk*384 + tile*32;

        // ---- A: stage z(tile) in-phase ----
        {
            const float* zp = zbase + (size_t)tile * 4096;
            float4 f0 = *(const float4*)(zp + 0);
            float4 f1 = *(const float4*)(zp + 4);
            float4 f2 = *(const float4*)(zp + 8);
            float4 f3 = *(const float4*)(zp + 12);
            uint4* dst = (uint4*)&z_l[sidx];
            dst[0] = uint4{pk2(f0.x,f0.y), pk2(f0.z,f0.w), pk2(f1.x,f1.y), pk2(f1.z,f1.w)};
            dst[1] = uint4{pk2(f2.x,f2.y), pk2(f2.z,f2.w), pk2(f3.x,f3.y), pk2(f3.z,f3.w)};
        }
        __syncthreads();

        // ---- B1: zB = z@Wb via MFMA (W0 rows 0-15, W1 rows 16-31) ----
        if (wv < 2) {
            f32x4 ab = {0,0,0,0};
            #pragma unroll
            for (int ks = 0; ks < 4; ks++) {
                short8 bf = *(const short8*)&wbT_l[lm*136 + ks*32 + g*8];
                int jr = wv*16 + lm;
                int ch = (jr >> 2)*8 + ks*2 + (g >> 1);
                int cp = ch + HOFF(ch >> 4);
                short8 a = *(const short8*)&z_l[cp*88 + (jr & 3)*16 + (g & 1)*8];
                ab = __builtin_amdgcn_mfma_f32_16x16x32_bf16(a, bf, ab, 0, 0, 0);
            }
            if (lm < 12) {
                #pragma unroll
                for (int r = 0; r < 4; r++)
                    zb_l[(wv*16 + g*4 + r)*13 + lm] = ab[r];
            }
        }
        __syncthreads();

        // ---- B2: EK-dot logits, 384 items: id=t, plus id=t+128 for t>=128 ----
        {
            auto b2item = [&](int id) {
                int jq = (id * 21846) >> 18;         // id/12 for id<384
                int h  = id - jq*12;
                float Bv = zb_l[jq*13 + h];
                const float* eqh = eq_l + h*33;
                const unsigned short* ek = EKw + ((size_t)(j0 + jq)*12 + h)*32;
                short8 e0 = *(const short8*)(ek);
                short8 e1 = *(const short8*)(ek + 8);
                short8 e2 = *(const short8*)(ek + 16);
                short8 e3 = *(const short8*)(ek + 24);
                float a0 = Bv * NS_B, a1 = 0, a2 = 0, a3 = 0;
                #pragma unroll
                for (int c = 0; c < 8; c++) a0 += eqh[c]      * bf2f((unsigned short)e0[c]);
                #pragma unroll
                for (int c = 0; c < 8; c++) a1 += eqh[8 + c]  * bf2f((unsigned short)e1[c]);
                #pragma unroll
                for (int c = 0; c < 8; c++) a2 += eqh[16 + c] * bf2f((unsigned short)e2[c]);
                #pragma unroll
                for (int c = 0; c < 6; c++) a3 += eqh[24 + c] * bf2f((unsigned short)e3[c]);
                // isolated mask pair (exact cancel when both masks = 1)
                float mterm = eqh[30] * bf2f((unsigned short)e3[6]);
                mterm += eqh[31] * bf2f((unsigned short)e3[7]);
                float acc = ((a0 + a1) + (a2 + a3)) + mterm;
                float p = __expf(acc);
                p_l[jq*17 + h]  = p;
                pT_l[h*40 + jq] = f2bf(p);
            };
            b2item(t);
            if (t >= 128) b2item(t + 128);
        }
        __syncthreads();

        // ---- C: O_pair MFMA + V-row tasks + den ----
        {
            const int nt0 = wv*2;
            short8 ap = *(const short8*)((const char*)pT_l + lm*80 + g*16);
            short8 b0, b1;
            #pragma unroll
            for (int e = 0; e < 8; e++) {
                int jje = g*8 + e;
                int su  = (jje >> 2)*8;
                int ro  = (jje & 3)*16;
                int cp0 = su + nt0 + HOFF(g);
                b0[e] = (short)z_l[cp0*88 + ro + lm];
                b1[e] = (short)z_l[(cp0 + 1)*88 + ro + lm];
            }
            opA = __builtin_amdgcn_mfma_f32_16x16x32_bf16(ap, b0, opA, 0, 0, 0);
            opB = __builtin_amdgcn_mfma_f32_16x16x32_bf16(ap, b1, opB, 0, 0, 0);
        }
        {
            const unsigned short* r1 = rp1 + j0;
            const unsigned short* r2 = rp2 + j0;
            float s1a = 0, s1b = 0, s2a = 0, s2b = 0;
            #pragma unroll
            for (int q = 0; q < 4; q++) {
                short8 va = *(const short8*)(r1 + q*8);
                short8 vb;
                if (has2) vb = *(const short8*)(r2 + q*8);
                float pa = 0, pbv2 = 0;
                #pragma unroll
                for (int e = 0; e < 8; e++) {
                    int j2 = q*8 + e;
                    pa   += p_l[j2*17 + h1] * bf2f((unsigned short)va[e]);
                    if (has2) pbv2 += p_l[j2*17 + h2] * bf2f((unsigned short)vb[e]);
                }
                if (q & 1) { s1b += pa; s2b += pbv2; }
                else       { s1a += pa; s2a += pbv2; }
            }
            acc1 += s1a + s1b;
            if (has2) acc2 += s2a + s2b;
            if (denh >= 0) {
                float da = 0, db = 0;
                #pragma unroll
                for (int j2 = 0; j2 < 16; j2++) da += p_l[j2*17 + denh];
                #pragma unroll
                for (int j2 = 16; j2 < 32; j2++) db += p_l[j2*17 + denh];
                dn += da + db;
            }
        }
        __syncthreads();   // z_l/p_l reads done; next A/B2 may overwrite
    }

    // ------- write partials -------
    float* pb = part3 + (size_t)blockIdx.x * 2560;
    pb[t] = acc1;                       // O row t (t<192) or V3 row t-192
    if (has2) pb[t + 256] = acc2;       // V3 row t+64
    if (denh >= 0) pb[2304 + denh] = dn;
    {
        const int nt0 = wv*2;
        #pragma unroll
        for (int r = 0; r < 4; r++) {
            int h = g*4 + r;
            if (h < 12) {
                pb[768 + h*128 + nt0*16 + lm]       = opA[r];
                pb[768 + h*128 + (nt0 + 1)*16 + lm] = opB[r];
            }
        }
    }
}

// ---------------------------------------------------------------------------
// Kernel 3b: combine 2 j-chunks, divide by den, rotate O3, write OF row.
// ---------------------------------------------------------------------------
__global__ __launch_bounds__(256) void combine_kernel(
    const float* __restrict__ part3, const float* __restrict__ rots,
    const float* __restrict__ trans, unsigned short* __restrict__ OF)
{
    const int i = blockIdx.x;
    const int t = threadIdx.x;
    const float* pa = part3 + (size_t)i*2*2560;
    const float* pb = pa + 2560;
    __shared__ float den_s[12];
    if (t < 12) den_s[t] = pa[2304 + t] + pb[2304 + t];
    __syncthreads();

    const size_t ofb = (size_t)i * 2112;
    if (t < 192) OF[ofb + t] = f2bf((pa[t] + pb[t]) / den_s[t >> 4]);
    if (t < 96) {
        int h = t >> 3, v = t & 7;
        float den = den_s[h];
        int base = 192 + t*3;
        float m0 = (pa[base+0] + pb[base+0]) / den - trans[i*3+0];
        float m1 = (pa[base+1] + pb[base+1]) / den - trans[i*3+1];
        float m2 = (pa[base+2] + pb[base+2]) / den - trans[i*3+2];
        const float* R = rots + (size_t)i*9;
        float r0v = R[0]*m0 + R[3]*m1 + R[6]*m2;
        float r1v = R[1]*m0 + R[4]*m1 + R[7]*m2;
        float r2v = R[2]*m0 + R[5]*m1 + R[8]*m2;
        float nrm = sqrtf(r0v*r0v + r1v*r1v + r2v*r2v + 1e-20f);
        int hv = h*8 + v;
        OF[ofb + 192 + hv] = f2bf(r0v);
        OF[ofb + 288 + hv] = f2bf(r1v);
        OF[ofb + 384 + hv] = f2bf(r2v);
        OF[ofb + 480 + hv] = f2bf(nrm);
    }
    for (int u = t; u < 1536; u += 256) {
        OF[ofb + 576 + u] = f2bf((pa[768 + u] + pb[768 + u]) / den_s[u >> 7]);
    }
}

// ---------------------------------------------------------------------------
// Kernel 4: out = OF(bf16) @ Wo (f32), K-split partials (deterministic).
// ---------------------------------------------------------------------------
__global__ __launch_bounds__(256) void out_gemm(
    const unsigned short* __restrict__ OF, const float* __restrict__ Wo,
    float* __restrict__ part)
{
    __shared__ __align__(16) float aT[32 * 132];
    __shared__ __align__(16) float bt[32 * 68];
    const int t  = threadIdx.x;
    const int i0 = blockIdx.x * 128;
    const int c0 = blockIdx.y * 64;
    const int k0 = blockIdx.z * 352;
    const int r0 = (t & 15) * 8;
    const int c4 = (t >> 4) * 4;

    float acc[8][4] = {};

    for (int kt = 0; kt < 11; kt++) {
        const int kk0 = k0 + kt*32;
        __syncthreads();
        {
            int r = t >> 1, kh = (t & 1) * 16;
            const unsigned short* apg = OF + (size_t)(i0 + r)*2112 + kk0 + kh;
            short8 v0 = *(const short8*)apg;
            short8 v1 = *(const short8*)(apg + 8);
            #pragma unroll
            for (int e = 0; e < 8; e++) aT[(kh + e)*132 + r]     = bf2f((unsigned short)v0[e]);
            #pragma unroll
            for (int e = 0; e < 8; e++) aT[(kh + 8 + e)*132 + r] = bf2f((unsigned short)v1[e]);
        }
        {
            int k = t >> 3, c8 = (t & 7) * 8;
            const float* wpg = Wo + (size_t)(kk0 + k)*384 + c0 + c8;
            *(float4*)&bt[k*68 + c8]     = *(const float4*)wpg;
            *(float4*)&bt[k*68 + c8 + 4] = *(const float4*)(wpg + 4);
        }
        __syncthreads();
        #pragma unroll 4
        for (int kk = 0; kk < 32; kk++) {
            float4 a0 = *(float4*)&aT[kk*132 + r0];
            float4 a1 = *(float4*)&aT[kk*132 + r0 + 4];
            float4 bv = *(float4*)&bt[kk*68 + c4];
            #pragma unroll
            for (int ci = 0; ci < 4; ci++) {
                float b = ((const float*)&bv)[ci];
                acc[0][ci] += ((const float*)&a0)[0] * b;
                acc[1][ci] += ((const float*)&a0)[1] * b;
                acc[2][ci] += ((const float*)&a0)[2] * b;
                acc[3][ci] += ((const float*)&a0)[3] * b;
                acc[4][ci] += ((const float*)&a1)[0] * b;
                acc[5][ci] += ((const float*)&a1)[1] * b;
                acc[6][ci] += ((const float*)&a1)[2] * b;
                acc[7][ci] += ((const float*)&a1)[3] * b;
            }
        }
    }

    float* pbv = part + (size_t)blockIdx.z * 294912;
    #pragma unroll
    for (int ri = 0; ri < 8; ri++) {
        float4 o = {acc[ri][0], acc[ri][1], acc[ri][2], acc[ri][3]};
        *(float4*)&pbv[(size_t)(i0 + r0 + ri)*384 + c0 + c4] = o;
    }
}

// ---------------------------------------------------------------------------
// Kernel 5: reduce 6 K-split partials + bias -> out (f32)
// ---------------------------------------------------------------------------
__global__ __launch_bounds__(256) void reduce_out(
    const float* __restrict__ part, const float* __restrict__ bo,
    float* __restrict__ out)
{
    int idx = blockIdx.x * 256 + threadIdx.x;
    float v = bo[idx % 384];
    #pragma unroll
    for (int s = 0; s < 6; s++) v += part[(size_t)s * 294912 + idx];
    out[idx] = v;
}

// ---------------------------------------------------------------------------
extern "C" void kernel_launch(void* const* d_in, const int* in_sizes, int n_in,
                              void* d_out, int out_size, void* d_ws, size_t ws_size,
                              hipStream_t stream) {
    const float* s     = (const float*)d_in[0];
    const float* z     = (const float*)d_in[1];
    const float* rots  = (const float*)d_in[2];
    const float* trans = (const float*)d_in[3];
    const float* mask  = (const float*)d_in[4];
    const float* Wq    = (const float*)d_in[5];
    const float* bq    = (const float*)d_in[6];
    const float* Wkv   = (const float*)d_in[7];
    const float* bkv   = (const float*)d_in[8];
    const float* Wq3   = (const float*)d_in[9];
    const float* bq3   = (const float*)d_in[10];
    const float* Wkv3  = (const float*)d_in[11];
    const float* bkv3  = (const float*)d_in[12];
    const float* Wb    = (const float*)d_in[13];
    const float* bb    = (const float*)d_in[14];
    const float* hw    = (const float*)d_in[15];
    const float* Wo    = (const float*)d_in[16];
    const float* bo    = (const float*)d_in[17];
    float* out = (float*)d_out;

    char* ws = (char*)d_ws;
    float*          Qw   = (float*)(ws + 0);              // 589824 B
    float*          Q3w  = (float*)(ws + 589824);         // 442368 B
    unsigned short* Kw   = (unsigned short*)(ws + 1032192);  // 294912 B
    unsigned short* Vt   = (unsigned short*)(ws + 1327104);  // 294912 B
    float*          K3w  = (float*)(ws + 1622016);        // 442368 B
    unsigned short* V3t  = (unsigned short*)(ws + 2064384);  // 442368 B
    float*          P3q  = (float*)(ws + 2506752);        // 442368 B
    float*          P3kv = (float*)(ws + 2949120);        // 1327104 B
    unsigned short* EQw  = (unsigned short*)(ws + 4276224);  // 589824 B
    unsigned short* EKw  = (unsigned short*)(ws + 4866048);  // 589824 B
    unsigned short* OF   = (unsigned short*)(ws + 5455872);  // 3244032 B
    float*          part3 = (float*)(ws + 8699904);       // 15728640 B
    float*          part  = (float*)(ws + 8699904);       // shared (disjoint lifetime)

    proj_kernel<<<dim3(24, 9), 256, 0, stream>>>(
        s, Wq, bq, Wkv, bkv, Wq3, bq3, Wkv3, bkv3, Qw, Kw, Vt, P3q, P3kv);
    rot3_kernel<<<768, 192, 0, stream>>>(P3q, P3kv, rots, trans, Q3w, K3w, V3t);
    ek_kernel<<<192, 256, 0, stream>>>(Qw, Kw, Q3w, K3w, mask, hw, bb, EQw, EKw);
    ipa_main<<<1536, 256, 0, stream>>>(z, Wb, EQw, EKw, Vt, V3t, part3);
    combine_kernel<<<768, 256, 0, stream>>>(part3, rots, trans, OF);
    out_gemm<<<dim3(6, 6, 6), 256, 0, stream>>>(OF, Wo, part);
    reduce_out<<<1152, 256, 0, stream>>>(part, bo, out);
}

// Round 10
// 269.995 us; speedup vs baseline: 1.9933x; 1.9933x over previous
//
#include <hip/hip_runtime.h>
#include <cstdint>

// ---------------------------------------------------------------------------
// InvariantPointAttention fused kernel set for MI355X (gfx950)
// N=768, C_S=384, C_Z=128, C_IPA=16, H=12, NQ=4, NV=8
// ipa_main/proj/rot3/combine: the R4-benched artifacts (196us ipa, no spill).
// out_gemm: replaced with MFMA full-K GEMM (+ fused bias), Wo pre-transposed
// to bf16 by wot_kernel.
// ---------------------------------------------------------------------------

typedef __attribute__((ext_vector_type(8))) short short8;
typedef __attribute__((ext_vector_type(4))) short short4_t;
typedef __attribute__((ext_vector_type(4))) float f32x4;

__device__ __forceinline__ unsigned short f2bf(float f) {
    unsigned u = __float_as_uint(f);
    u = (u + 0x7FFFu + ((u >> 16) & 1u)) >> 16;   // RNE
    return (unsigned short)u;
}
__device__ __forceinline__ float bf2f(unsigned short s) {
    return __uint_as_float(((unsigned)s) << 16);
}
__device__ __forceinline__ unsigned pk2(float lo, float hi) {
    return (unsigned)f2bf(lo) | ((unsigned)f2bf(hi) << 16);
}
// subtile placement offset: H[g] = {0,6,20,26}; 44*H[g] mod 32 = {0,8,16,24}
__device__ __forceinline__ int HOFF(int gg) {
    return gg * 6 + ((gg & 2) << 2);
}

// ---------------------------------------------------------------------------
// Kernel 1: fused projection GEMM.  s (768x384) @ [Wq|Wkv|Wq3|Wkv3] (384x1152)
// ---------------------------------------------------------------------------
__global__ __launch_bounds__(256) void proj_kernel(
    const float* __restrict__ s,
    const float* __restrict__ Wq,   const float* __restrict__ bq,
    const float* __restrict__ Wkv,  const float* __restrict__ bkv,
    const float* __restrict__ Wq3,  const float* __restrict__ bq3,
    const float* __restrict__ Wkv3, const float* __restrict__ bkv3,
    float* __restrict__ Qw, unsigned short* __restrict__ Kw,
    unsigned short* __restrict__ Vw,
    float* __restrict__ P3q, float* __restrict__ P3kv)
{
    __shared__ __align__(16) float s_lds[32 * 384];
    const int t  = threadIdx.x;
    const int r0 = blockIdx.x * 32;
    const int c0 = blockIdx.y * 128;

    for (int u = t; u < 3072; u += 256) {
        int r = u / 96, c4 = u - r * 96;
        *(float4*)&s_lds[r * 384 + c4 * 4] =
            *(const float4*)&s[(size_t)(r0 + r) * 384 + c4 * 4];
    }
    __syncthreads();

    const int rg = t >> 6;
    const int lc = t & 63;
    const int colA = c0 + lc;
    const int colB = c0 + lc + 64;

    const float *wpA, *wpB; int ldA, ldB; float biasA, biasB;
    {
        int col = colA;
        if (col < 192)      { wpA = Wq   + col;       ldA = 192; biasA = bq[col]; }
        else if (col < 576) { wpA = Wkv  + (col-192); ldA = 384; biasA = bkv[col-192]; }
        else if (col < 720) { wpA = Wq3  + (col-576); ldA = 144; biasA = bq3[col-576]; }
        else                { wpA = Wkv3 + (col-720); ldA = 432; biasA = bkv3[col-720]; }
        col = colB;
        if (col < 192)      { wpB = Wq   + col;       ldB = 192; biasB = bq[col]; }
        else if (col < 576) { wpB = Wkv  + (col-192); ldB = 384; biasB = bkv[col-192]; }
        else if (col < 720) { wpB = Wq3  + (col-576); ldB = 144; biasB = bq3[col-576]; }
        else                { wpB = Wkv3 + (col-720); ldB = 432; biasB = bkv3[col-720]; }
    }

    float acc0[8] = {}, acc1[8] = {};
    for (int k = 0; k < 384; k += 4) {
        float4 sv[8];
        #pragma unroll
        for (int r = 0; r < 8; r++)
            sv[r] = *(const float4*)&s_lds[(rg*8 + r) * 384 + k];
        #pragma unroll
        for (int kk = 0; kk < 4; kk++) {
            float w0 = wpA[(k + kk) * ldA];
            float w1 = wpB[(k + kk) * ldB];
            #pragma unroll
            for (int r = 0; r < 8; r++) {
                float sval = ((const float*)&sv[r])[kk];
                acc0[r] += sval * w0;
                acc1[r] += sval * w1;
            }
        }
    }

    #pragma unroll
    for (int q = 0; q < 2; q++) {
        int col   = q ? colB : colA;
        float bia = q ? biasB : biasA;
        #pragma unroll
        for (int r = 0; r < 8; r++) {
            int row = r0 + rg*8 + r;
            float v = (q ? acc1[r] : acc0[r]) + bia;
            if (col < 192) {
                Qw[(size_t)row*192 + col] = v;
            } else if (col < 576) {
                int c = col - 192, h = c >> 5, sub = c & 31;
                if (sub < 16) Kw[(size_t)row*192 + h*16 + sub]      = f2bf(v);
                else          Vw[(size_t)row*192 + h*16 + (sub-16)] = f2bf(v);
            } else if (col < 720) {
                P3q[(size_t)row*144 + (col-576)] = v;
            } else {
                P3kv[(size_t)row*432 + (col-720)] = v;
            }
        }
    }
}

// ---------------------------------------------------------------------------
// Kernel 2: rotate/translate the projected points. (R4 version)
// ---------------------------------------------------------------------------
__global__ __launch_bounds__(192) void rot3_kernel(
    const float* __restrict__ P3q, const float* __restrict__ P3kv,
    const float* __restrict__ rots, const float* __restrict__ trans,
    float* __restrict__ Q3w, unsigned short* __restrict__ K3w,
    unsigned short* __restrict__ V3w)
{
    const int n = blockIdx.x;
    const int t = threadIdx.x;
    float R[9];
    #pragma unroll
    for (int u = 0; u < 9; u++) R[u] = rots[n*9 + u];
    float T0 = trans[n*3+0], T1 = trans[n*3+1], T2 = trans[n*3+2];

    float p0, p1, p2;
    if (t < 48) {
        p0 = P3q[(size_t)n*144 + t];
        p1 = P3q[(size_t)n*144 + 48 + t];
        p2 = P3q[(size_t)n*144 + 96 + t];
    } else {
        int k = t - 48;
        p0 = P3kv[(size_t)n*432 + k];
        p1 = P3kv[(size_t)n*432 + 144 + k];
        p2 = P3kv[(size_t)n*432 + 288 + k];
    }
    float o0 = R[0]*p0 + R[1]*p1 + R[2]*p2 + T0;
    float o1 = R[3]*p0 + R[4]*p1 + R[5]*p2 + T1;
    float o2 = R[6]*p0 + R[7]*p1 + R[8]*p2 + T2;

    if (t < 48) {
        Q3w[(size_t)n*144 + t*3 + 0] = o0;
        Q3w[(size_t)n*144 + t*3 + 1] = o1;
        Q3w[(size_t)n*144 + t*3 + 2] = o2;
    } else {
        int k = t - 48, h = k / 12, m = k % 12;
        if (m < 4) {
            size_t base = (size_t)n*144 + (h*4 + m)*3;
            K3w[base+0] = f2bf(o0); K3w[base+1] = f2bf(o1); K3w[base+2] = f2bf(o2);
        } else {
            size_t base = (size_t)n*384 + (h*8 + (m-4))*4;
            V3w[base+0] = f2bf(o0); V3w[base+1] = f2bf(o1); V3w[base+2] = f2bf(o2);
        }
    }
}

// ---------------------------------------------------------------------------
// Kernel 3: fused IPA attention (the R4-benched artifact, verbatim).
// ---------------------------------------------------------------------------
__global__ __launch_bounds__(256, 4) void ipa_main(
    const float* __restrict__ z, const float* __restrict__ mask,
    const float* __restrict__ Wb, const float* __restrict__ bb,
    const float* __restrict__ hw,
    const float* __restrict__ Qw, const unsigned short* __restrict__ Kw,
    const unsigned short* __restrict__ Vw,
    const float* __restrict__ Q3w, const unsigned short* __restrict__ K3w,
    const unsigned short* __restrict__ V3w,
    float* __restrict__ part3)
{
    __shared__ __align__(16) unsigned short z_l[90 * 88];     // 15.8 KB
    __shared__ __align__(16) unsigned short wbT_l[16 * 136];
    __shared__ __align__(16) float          p_l[32 * 17];
    __shared__ __align__(16) unsigned short pT_l[16 * 40];
    __shared__ __align__(16) float          Q_lds[192];
    __shared__ __align__(16) float          Q3_lds[144];
    __shared__ float hw_lds[12], bb_lds[12];

    const int i     = blockIdx.x >> 1;
    const int chunk = blockIdx.x & 1;
    const int t    = threadIdx.x;
    const int lane = t & 63;
    const int wv   = t >> 6;
    const int g    = lane >> 4;
    const int lm   = lane & 15;

    // ------- per-block init -------
    if (t < 192) Q_lds[t]  = Qw[(size_t)i*192 + t];
    if (t < 144) Q3_lds[t] = Q3w[(size_t)i*144 + t];
    if (t < 12) {
        hw_lds[t] = log1pf(__expf(hw[t])) * 0.13608276348795434f;
        bb_lds[t] = bb[t];
    }
    if (t < 160) pT_l[480 + t] = 0;
    for (int u = t; u < 1536; u += 256) {
        int h = u % 12, c = u / 12;
        wbT_l[h*136 + c] = f2bf(Wb[c*12 + h]);
    }
    const float mask_i = mask[i];

    // accumulators
    f32x4 opA = {0,0,0,0}, opB = {0,0,0,0};
    float oacc = 0.0f;
    float o3x = 0, o3y = 0, o3z = 0;
    float dena = 0;
    const int oh = t >> 4, oc = t & 15;
    int o3h = -1, o3v = 0, o3j0 = 0, o3j1 = 32, o3slot = 0;
    if (t >= 192)    { o3h = (t - 192) >> 3;      o3v = (t - 192) & 7; }
    else if (t < 32) { o3h = 8 + (t >> 3);        o3v = t & 7;        o3j1 = 16; }
    else if (t < 64) { o3h = 8 + ((t - 32) >> 3); o3v = (t - 32) & 7; o3j0 = 16; o3slot = 1; }
    const int denh = (t >= 64 && t < 76) ? (t - 64) : -1;

    const int jj  = t >> 3, c16 = t & 7;
    const float* zbase = z + ((size_t)i*768 + chunk*384 + jj)*128 + c16*16;
    const int chS  = (jj >> 2)*8 + c16;                 // subtile 0..63
    const int chP  = chS + HOFF(chS >> 4);              // placed slot
    const int sidx = chP*88 + (jj & 3)*16;              // element index

    __syncthreads();

    for (int tile = 0; tile < 12; tile++) {
        const int j0 = chunk*384 + tile*32;

        // ---- phase A: load z tile, convert, store placed-subtile LDS ----
        {
            const float* zp = zbase + (size_t)tile * 32 * 128;
            float4 f0 = *(const float4*)(zp + 0);
            float4 f1 = *(const float4*)(zp + 4);
            float4 f2 = *(const float4*)(zp + 8);
            float4 f3 = *(const float4*)(zp + 12);
            uint4* dst = (uint4*)&z_l[sidx];
            dst[0] = uint4{pk2(f0.x,f0.y), pk2(f0.z,f0.w), pk2(f1.x,f1.y), pk2(f1.z,f1.w)};
            dst[1] = uint4{pk2(f2.x,f2.y), pk2(f2.z,f2.w), pk2(f3.x,f3.y), pk2(f3.z,f3.w)};
        }
        __syncthreads();

        // ---- phase B1: B = z@Wb via MFMA, waves 0 and 1 ----
        if (wv < 2) {
            f32x4 ab = {0,0,0,0};
            const int jt = wv;
            #pragma unroll
            for (int ks = 0; ks < 4; ks++) {
                short8 bf = *(const short8*)&wbT_l[lm*136 + ks*32 + g*8];
                int jr = jt*16 + lm;
                int ch = (jr >> 2)*8 + ks*2 + (g >> 1);
                int cp = ch + HOFF(ch >> 4);
                short8 a = *(const short8*)&z_l[cp*88 + (jr & 3)*16 + (g & 1)*8];
                ab = __builtin_amdgcn_mfma_f32_16x16x32_bf16(a, bf, ab, 0, 0, 0);
            }
            if (lm < 12) {
                #pragma unroll
                for (int r = 0; r < 4; r++)
                    p_l[(jt*16 + g*4 + r)*17 + lm] = ab[r];
            }
        }
        __syncthreads();

        // ---- phase B2: finish logits, exp, store p (f32) and p^T (bf16) ----
        #pragma unroll
        for (int rep = 0; rep < 2; rep++) {
            int pr = t + rep*256;
            if (pr < 384) {
                int jjq = pr / 12;
                int h   = pr - jjq*12;
                int j   = j0 + jjq;
                float Bv = p_l[jjq*17 + h];
                const unsigned short* kp = Kw + (size_t)j*192 + h*16;
                short8 kA = *(const short8*)(kp);
                short8 kB = *(const short8*)(kp + 8);
                float qk = 0.0f;
                #pragma unroll
                for (int e = 0; e < 8; e++) qk += Q_lds[h*16 + e]     * bf2f((unsigned short)kA[e]);
                #pragma unroll
                for (int e = 0; e < 8; e++) qk += Q_lds[h*16 + 8 + e] * bf2f((unsigned short)kB[e]);
                const unsigned short* k3p = K3w + (size_t)j*144 + h*12;
                short4_t c0v = *(const short4_t*)(k3p);
                short4_t c1v = *(const short4_t*)(k3p + 4);
                short4_t c2v = *(const short4_t*)(k3p + 8);
                float d2 = 0.0f;
                #pragma unroll
                for (int e = 0; e < 4; e++) { float d = Q3_lds[h*12 + e]     - bf2f((unsigned short)c0v[e]); d2 += d*d; }
                #pragma unroll
                for (int e = 0; e < 4; e++) { float d = Q3_lds[h*12 + 4 + e] - bf2f((unsigned short)c1v[e]); d2 += d*d; }
                #pragma unroll
                for (int e = 0; e < 4; e++) { float d = Q3_lds[h*12 + 8 + e] - bf2f((unsigned short)c2v[e]); d2 += d*d; }
                float mj = mask[j];
                float lg = qk * 0.14433756729740643f
                         + (Bv + bb_lds[h]) * 0.5773502691896258f
                         - 0.5f * hw_lds[h] * d2
                         + (mask_i * mj - 1.0f) * 1e9f;
                float p = __expf(lg);
                p_l[jjq*17 + h]  = p;
                pT_l[h*40 + jjq] = f2bf(p);
            }
        }
        __syncthreads();

        // ---- phase C: O_pair MFMA (conflict-free placed subtiles) ----
        {
            const int nt0 = wv*2;
            short8 ap = *(const short8*)((const char*)pT_l + lm*80 + g*16);
            short8 b0, b1;
            #pragma unroll
            for (int e = 0; e < 8; e++) {
                int jje = g*8 + e;
                int su  = (jje >> 2)*8;
                int ro  = (jje & 3)*16;
                int cp0 = su + nt0 + HOFF(g);       // (su+nt0)>>4 == g
                b0[e] = (short)z_l[cp0*88 + ro + lm];
                b1[e] = (short)z_l[(cp0 + 1)*88 + ro + lm];
            }
            opA = __builtin_amdgcn_mfma_f32_16x16x32_bf16(ap, b0, opA, 0, 0, 0);
            opB = __builtin_amdgcn_mfma_f32_16x16x32_bf16(ap, b1, opB, 0, 0, 0);
        }
        if (t < 192) {
            #pragma unroll 8
            for (int jjq = 0; jjq < 32; jjq++) {
                float p = p_l[jjq*17 + oh];
                oacc += p * bf2f(Vw[(size_t)(j0 + jjq)*192 + oh*16 + oc]);
            }
        }
        if (o3h >= 0) {
            #pragma unroll 8
            for (int jjq = o3j0; jjq < o3j1; jjq++) {
                float p = p_l[jjq*17 + o3h];
                short4_t v4 = *(const short4_t*)(V3w + (size_t)(j0 + jjq)*384 + (o3h*8 + o3v)*4);
                o3x += p * bf2f((unsigned short)v4[0]);
                o3y += p * bf2f((unsigned short)v4[1]);
                o3z += p * bf2f((unsigned short)v4[2]);
            }
        }
        if (denh >= 0) {
            #pragma unroll 8
            for (int jjq = 0; jjq < 32; jjq++) dena += p_l[jjq*17 + denh];
        }
        __syncthreads();
    }

    // ------- write partials -------
    float* pb = part3 + (size_t)blockIdx.x * 2560;
    if (t < 192) pb[t] = oacc;
    if (o3h >= 0) {
        int base = 192 + o3slot*288 + (o3h*8 + o3v)*3;
        pb[base+0] = o3x; pb[base+1] = o3y; pb[base+2] = o3z;
    }
    if (denh >= 0) pb[2304 + denh] = dena;
    {
        const int nt0 = wv*2;
        #pragma unroll
        for (int r = 0; r < 4; r++) {
            int h = g*4 + r;
            if (h < 12) {
                pb[768 + h*128 + nt0*16 + lm]       = opA[r];
                pb[768 + h*128 + (nt0 + 1)*16 + lm] = opB[r];
            }
        }
    }
}

// ---------------------------------------------------------------------------
// Kernel 3b: combine 2 j-chunks, divide by den, rotate O3, write OF row.
// ---------------------------------------------------------------------------
__global__ __launch_bounds__(256) void combine_kernel(
    const float* __restrict__ part3, const float* __restrict__ rots,
    const float* __restrict__ trans, unsigned short* __restrict__ OF)
{
    const int i = blockIdx.x;
    const int t = threadIdx.x;
    const float* pa = part3 + (size_t)i*2*2560;
    const float* pb = pa + 2560;
    __shared__ float den_s[12];
    if (t < 12) den_s[t] = pa[2304 + t] + pb[2304 + t];
    __syncthreads();

    const size_t ofb = (size_t)i * 2112;
    if (t < 192) OF[ofb + t] = f2bf((pa[t] + pb[t]) / den_s[t >> 4]);
    if (t < 96) {
        int h = t >> 3, v = t & 7;
        float den = den_s[h];
        int base = 192 + t*3;
        float m0 = pa[base+0] + pb[base+0];
        float m1 = pa[base+1] + pb[base+1];
        float m2 = pa[base+2] + pb[base+2];
        if (h >= 8) {   // slot B contributions (j 16..31 halves)
            m0 += pa[base+288+0] + pb[base+288+0];
            m1 += pa[base+288+1] + pb[base+288+1];
            m2 += pa[base+288+2] + pb[base+288+2];
        }
        m0 = m0 / den - trans[i*3+0];
        m1 = m1 / den - trans[i*3+1];
        m2 = m2 / den - trans[i*3+2];
        const float* R = rots + (size_t)i*9;
        float r0v = R[0]*m0 + R[3]*m1 + R[6]*m2;
        float r1v = R[1]*m0 + R[4]*m1 + R[7]*m2;
        float r2v = R[2]*m0 + R[5]*m1 + R[8]*m2;
        float nrm = sqrtf(r0v*r0v + r1v*r1v + r2v*r2v + 1e-20f);
        int hv = h*8 + v;
        OF[ofb + 192 + hv] = f2bf(r0v);
        OF[ofb + 288 + hv] = f2bf(r1v);
        OF[ofb + 384 + hv] = f2bf(r2v);
        OF[ofb + 480 + hv] = f2bf(nrm);
    }
    for (int u = t; u < 1536; u += 256) {
        OF[ofb + 576 + u] = f2bf((pa[768 + u] + pb[768 + u]) / den_s[u >> 7]);
    }
}

// ---------------------------------------------------------------------------
// Kernel 4a: WoT[c][k] = bf16(Wo[k][c]).  2112x384 -> 384x2112.
// grid 396, block 256 (101376 threads, one 8-k chunk each).
// ---------------------------------------------------------------------------
__global__ __launch_bounds__(256) void wot_kernel(
    const float* __restrict__ Wo, unsigned short* __restrict__ WoT)
{
    int id = blockIdx.x * 256 + threadIdx.x;   // < 101376 = 384*264
    int c  = id % 384;
    int k8 = id / 384;                          // < 264
    unsigned short tmp[8];
    #pragma unroll
    for (int e = 0; e < 8; e++)
        tmp[e] = f2bf(Wo[(size_t)(k8*8 + e)*384 + c]);
    uint4 o;
    o.x = (unsigned)tmp[0] | ((unsigned)tmp[1] << 16);
    o.y = (unsigned)tmp[2] | ((unsigned)tmp[3] << 16);
    o.z = (unsigned)tmp[4] | ((unsigned)tmp[5] << 16);
    o.w = (unsigned)tmp[6] | ((unsigned)tmp[7] << 16);
    *(uint4*)&WoT[(size_t)c*2112 + k8*8] = o;
}

// ---------------------------------------------------------------------------
// Kernel 4b: out = OF(bf16) @ WoT^T (bf16) + bo, via MFMA, full K (2112).
// grid (24, 3): rows 32/block, cols 128/block (32/wave). No LDS.
// A-frag: lane (g,lm): OF[i0+ri*16+lm][k + g*8 + e]
// B-frag: lane (g,lm): WoT[c0+ci*16+lm][k + g*8 + e]
// C/D:    col = lm, row = g*4 + r  (within 16x16 frag)
// ---------------------------------------------------------------------------
__global__ __launch_bounds__(256) void out_gemm2(
    const unsigned short* __restrict__ OF, const unsigned short* __restrict__ WoT,
    const float* __restrict__ bo, float* __restrict__ out)
{
    const int t = threadIdx.x;
    const int wv = t >> 6, lane = t & 63, g = lane >> 4, lm = lane & 15;
    const int i0 = blockIdx.x * 32;
    const int c0 = blockIdx.y * 128 + wv * 32;

    f32x4 acc00 = {0,0,0,0}, acc01 = {0,0,0,0};
    f32x4 acc10 = {0,0,0,0}, acc11 = {0,0,0,0};

    const unsigned short* a0p = OF  + (size_t)(i0 + lm)*2112      + g*8;
    const unsigned short* a1p = OF  + (size_t)(i0 + 16 + lm)*2112 + g*8;
    const unsigned short* b0p = WoT + (size_t)(c0 + lm)*2112      + g*8;
    const unsigned short* b1p = WoT + (size_t)(c0 + 16 + lm)*2112 + g*8;

    #pragma unroll 2
    for (int k = 0; k < 2112; k += 32) {
        short8 a0 = *(const short8*)(a0p + k);
        short8 a1 = *(const short8*)(a1p + k);
        short8 b0 = *(const short8*)(b0p + k);
        short8 b1 = *(const short8*)(b1p + k);
        acc00 = __builtin_amdgcn_mfma_f32_16x16x32_bf16(a0, b0, acc00, 0, 0, 0);
        acc01 = __builtin_amdgcn_mfma_f32_16x16x32_bf16(a0, b1, acc01, 0, 0, 0);
        acc10 = __builtin_amdgcn_mfma_f32_16x16x32_bf16(a1, b0, acc10, 0, 0, 0);
        acc11 = __builtin_amdgcn_mfma_f32_16x16x32_bf16(a1, b1, acc11, 0, 0, 0);
    }

    const int colA = c0 + lm, colB = c0 + 16 + lm;
    const float bA = bo[colA], bB = bo[colB];
    #pragma unroll
    for (int r = 0; r < 4; r++) {
        int rowA = i0 + g*4 + r;
        int rowB = i0 + 16 + g*4 + r;
        out[(size_t)rowA*384 + colA] = acc00[r] + bA;
        out[(size_t)rowA*384 + colB] = acc01[r] + bB;
        out[(size_t)rowB*384 + colA] = acc10[r] + bA;
        out[(size_t)rowB*384 + colB] = acc11[r] + bB;
    }
}

// ---------------------------------------------------------------------------
extern "C" void kernel_launch(void* const* d_in, const int* in_sizes, int n_in,
                              void* d_out, int out_size, void* d_ws, size_t ws_size,
                              hipStream_t stream) {
    const float* s     = (const float*)d_in[0];
    const float* z     = (const float*)d_in[1];
    const float* rots  = (const float*)d_in[2];
    const float* trans = (const float*)d_in[3];
    const float* mask  = (const float*)d_in[4];
    const float* Wq    = (const float*)d_in[5];
    const float* bq    = (const float*)d_in[6];
    const float* Wkv   = (const float*)d_in[7];
    const float* bkv   = (const float*)d_in[8];
    const float* Wq3   = (const float*)d_in[9];
    const float* bq3   = (const float*)d_in[10];
    const float* Wkv3  = (const float*)d_in[11];
    const float* bkv3  = (const float*)d_in[12];
    const float* Wb    = (const float*)d_in[13];
    const float* bb    = (const float*)d_in[14];
    const float* hw    = (const float*)d_in[15];
    const float* Wo    = (const float*)d_in[16];
    const float* bo    = (const float*)d_in[17];
    float* out = (float*)d_out;

    char* ws = (char*)d_ws;
    float*          Qw   = (float*)(ws + 0);                 // 589824 B
    float*          Q3w  = (float*)(ws + 589824);            // 442368 B
    unsigned short* Kw   = (unsigned short*)(ws + 1032192);  // 294912 B
    unsigned short* Vw   = (unsigned short*)(ws + 1327104);  // 294912 B
    unsigned short* K3w  = (unsigned short*)(ws + 1622016);  // 221184 B
    unsigned short* V3w  = (unsigned short*)(ws + 1843200);  // 589824 B
    float*          P3q  = (float*)(ws + 2433024);           // 442368 B
    float*          P3kv = (float*)(ws + 2875392);           // 1327104 B
    unsigned short* OF   = (unsigned short*)(ws + 4202496);  // 3244032 B
    float*          part3 = (float*)(ws + 7446528);          // 15728640 B (ends 23175168)
    unsigned short* WoT  = (unsigned short*)(ws + 23175168); // 1622016 B

    wot_kernel<<<396, 256, 0, stream>>>(Wo, WoT);
    proj_kernel<<<dim3(24, 9), 256, 0, stream>>>(
        s, Wq, bq, Wkv, bkv, Wq3, bq3, Wkv3, bkv3, Qw, Kw, Vw, P3q, P3kv);
    rot3_kernel<<<768, 192, 0, stream>>>(P3q, P3kv, rots, trans, Q3w, K3w, V3w);
    ipa_main<<<1536, 256, 0, stream>>>(
        z, mask, Wb, bb, hw, Qw, Kw, Vw, Q3w, K3w, V3w, part3);
    combine_kernel<<<768, 256, 0, stream>>>(part3, rots, trans, OF);
    out_gemm2<<<dim3(24, 3), 256, 0, stream>>>(OF, WoT, bo, out);
}

// Round 11
// 264.053 us; speedup vs baseline: 2.0381x; 1.0225x over previous
//
#include <hip/hip_runtime.h>
#include <cstdint>

// ---------------------------------------------------------------------------
// InvariantPointAttention fused kernel set for MI355X (gfx950)
// N=768, C_S=384, C_Z=128, C_IPA=16, H=12, NQ=4, NV=8
// ipa_main: R4 artifact + Q_lds/Q3_lds bank-conflict padding + B2 rebalance.
// out_gemm2: MFMA full-K GEMM with LDS-staged coalesced tiles.
// ---------------------------------------------------------------------------

typedef __attribute__((ext_vector_type(8))) short short8;
typedef __attribute__((ext_vector_type(4))) short short4_t;
typedef __attribute__((ext_vector_type(4))) float f32x4;

__device__ __forceinline__ unsigned short f2bf(float f) {
    unsigned u = __float_as_uint(f);
    u = (u + 0x7FFFu + ((u >> 16) & 1u)) >> 16;   // RNE
    return (unsigned short)u;
}
__device__ __forceinline__ float bf2f(unsigned short s) {
    return __uint_as_float(((unsigned)s) << 16);
}
__device__ __forceinline__ unsigned pk2(float lo, float hi) {
    return (unsigned)f2bf(lo) | ((unsigned)f2bf(hi) << 16);
}
// subtile placement offset: H[g] = {0,6,20,26}; 44*H[g] mod 32 = {0,8,16,24}
__device__ __forceinline__ int HOFF(int gg) {
    return gg * 6 + ((gg & 2) << 2);
}

// ---------------------------------------------------------------------------
// Kernel 1: fused projection GEMM.  s (768x384) @ [Wq|Wkv|Wq3|Wkv3] (384x1152)
// ---------------------------------------------------------------------------
__global__ __launch_bounds__(256) void proj_kernel(
    const float* __restrict__ s,
    const float* __restrict__ Wq,   const float* __restrict__ bq,
    const float* __restrict__ Wkv,  const float* __restrict__ bkv,
    const float* __restrict__ Wq3,  const float* __restrict__ bq3,
    const float* __restrict__ Wkv3, const float* __restrict__ bkv3,
    float* __restrict__ Qw, unsigned short* __restrict__ Kw,
    unsigned short* __restrict__ Vw,
    float* __restrict__ P3q, float* __restrict__ P3kv)
{
    __shared__ __align__(16) float s_lds[32 * 384];
    const int t  = threadIdx.x;
    const int r0 = blockIdx.x * 32;
    const int c0 = blockIdx.y * 128;

    for (int u = t; u < 3072; u += 256) {
        int r = u / 96, c4 = u - r * 96;
        *(float4*)&s_lds[r * 384 + c4 * 4] =
            *(const float4*)&s[(size_t)(r0 + r) * 384 + c4 * 4];
    }
    __syncthreads();

    const int rg = t >> 6;
    const int lc = t & 63;
    const int colA = c0 + lc;
    const int colB = c0 + lc + 64;

    const float *wpA, *wpB; int ldA, ldB; float biasA, biasB;
    {
        int col = colA;
        if (col < 192)      { wpA = Wq   + col;       ldA = 192; biasA = bq[col]; }
        else if (col < 576) { wpA = Wkv  + (col-192); ldA = 384; biasA = bkv[col-192]; }
        else if (col < 720) { wpA = Wq3  + (col-576); ldA = 144; biasA = bq3[col-576]; }
        else                { wpA = Wkv3 + (col-720); ldA = 432; biasA = bkv3[col-720]; }
        col = colB;
        if (col < 192)      { wpB = Wq   + col;       ldB = 192; biasB = bq[col]; }
        else if (col < 576) { wpB = Wkv  + (col-192); ldB = 384; biasB = bkv[col-192]; }
        else if (col < 720) { wpB = Wq3  + (col-576); ldB = 144; biasB = bq3[col-576]; }
        else                { wpB = Wkv3 + (col-720); ldB = 432; biasB = bkv3[col-720]; }
    }

    float acc0[8] = {}, acc1[8] = {};
    for (int k = 0; k < 384; k += 4) {
        float4 sv[8];
        #pragma unroll
        for (int r = 0; r < 8; r++)
            sv[r] = *(const float4*)&s_lds[(rg*8 + r) * 384 + k];
        #pragma unroll
        for (int kk = 0; kk < 4; kk++) {
            float w0 = wpA[(k + kk) * ldA];
            float w1 = wpB[(k + kk) * ldB];
            #pragma unroll
            for (int r = 0; r < 8; r++) {
                float sval = ((const float*)&sv[r])[kk];
                acc0[r] += sval * w0;
                acc1[r] += sval * w1;
            }
        }
    }

    #pragma unroll
    for (int q = 0; q < 2; q++) {
        int col   = q ? colB : colA;
        float bia = q ? biasB : biasA;
        #pragma unroll
        for (int r = 0; r < 8; r++) {
            int row = r0 + rg*8 + r;
            float v = (q ? acc1[r] : acc0[r]) + bia;
            if (col < 192) {
                Qw[(size_t)row*192 + col] = v;
            } else if (col < 576) {
                int c = col - 192, h = c >> 5, sub = c & 31;
                if (sub < 16) Kw[(size_t)row*192 + h*16 + sub]      = f2bf(v);
                else          Vw[(size_t)row*192 + h*16 + (sub-16)] = f2bf(v);
            } else if (col < 720) {
                P3q[(size_t)row*144 + (col-576)] = v;
            } else {
                P3kv[(size_t)row*432 + (col-720)] = v;
            }
        }
    }
}

// ---------------------------------------------------------------------------
// Kernel 2: rotate/translate the projected points. (R4 version)
// ---------------------------------------------------------------------------
__global__ __launch_bounds__(192) void rot3_kernel(
    const float* __restrict__ P3q, const float* __restrict__ P3kv,
    const float* __restrict__ rots, const float* __restrict__ trans,
    float* __restrict__ Q3w, unsigned short* __restrict__ K3w,
    unsigned short* __restrict__ V3w)
{
    const int n = blockIdx.x;
    const int t = threadIdx.x;
    float R[9];
    #pragma unroll
    for (int u = 0; u < 9; u++) R[u] = rots[n*9 + u];
    float T0 = trans[n*3+0], T1 = trans[n*3+1], T2 = trans[n*3+2];

    float p0, p1, p2;
    if (t < 48) {
        p0 = P3q[(size_t)n*144 + t];
        p1 = P3q[(size_t)n*144 + 48 + t];
        p2 = P3q[(size_t)n*144 + 96 + t];
    } else {
        int k = t - 48;
        p0 = P3kv[(size_t)n*432 + k];
        p1 = P3kv[(size_t)n*432 + 144 + k];
        p2 = P3kv[(size_t)n*432 + 288 + k];
    }
    float o0 = R[0]*p0 + R[1]*p1 + R[2]*p2 + T0;
    float o1 = R[3]*p0 + R[4]*p1 + R[5]*p2 + T1;
    float o2 = R[6]*p0 + R[7]*p1 + R[8]*p2 + T2;

    if (t < 48) {
        Q3w[(size_t)n*144 + t*3 + 0] = o0;
        Q3w[(size_t)n*144 + t*3 + 1] = o1;
        Q3w[(size_t)n*144 + t*3 + 2] = o2;
    } else {
        int k = t - 48, h = k / 12, m = k % 12;
        if (m < 4) {
            size_t base = (size_t)n*144 + (h*4 + m)*3;
            K3w[base+0] = f2bf(o0); K3w[base+1] = f2bf(o1); K3w[base+2] = f2bf(o2);
        } else {
            size_t base = (size_t)n*384 + (h*8 + (m-4))*4;
            V3w[base+0] = f2bf(o0); V3w[base+1] = f2bf(o1); V3w[base+2] = f2bf(o2);
        }
    }
}

// ---------------------------------------------------------------------------
// Kernel 3: fused IPA attention (R4 artifact + bank-conflict padding).
// Q_lds stride 17 (17h mod 32 distinct for h<12); Q3_lds stride 13.
// ---------------------------------------------------------------------------
__global__ __launch_bounds__(256, 4) void ipa_main(
    const float* __restrict__ z, const float* __restrict__ mask,
    const float* __restrict__ Wb, const float* __restrict__ bb,
    const float* __restrict__ hw,
    const float* __restrict__ Qw, const unsigned short* __restrict__ Kw,
    const unsigned short* __restrict__ Vw,
    const float* __restrict__ Q3w, const unsigned short* __restrict__ K3w,
    const unsigned short* __restrict__ V3w,
    float* __restrict__ part3)
{
    __shared__ __align__(16) unsigned short z_l[90 * 88];     // 15.8 KB
    __shared__ __align__(16) unsigned short wbT_l[16 * 136];
    __shared__ __align__(16) float          p_l[32 * 17];
    __shared__ __align__(16) unsigned short pT_l[16 * 40];
    __shared__ __align__(16) float          Q_lds[12 * 17];   // stride 17
    __shared__ __align__(16) float          Q3_lds[12 * 13];  // stride 13
    __shared__ float hw_lds[12], bb_lds[12];

    const int i     = blockIdx.x >> 1;
    const int chunk = blockIdx.x & 1;
    const int t    = threadIdx.x;
    const int lane = t & 63;
    const int wv   = t >> 6;
    const int g    = lane >> 4;
    const int lm   = lane & 15;

    // ------- per-block init -------
    if (t < 192) Q_lds[(t >> 4)*17 + (t & 15)] = Qw[(size_t)i*192 + t];
    if (t < 144) Q3_lds[(t / 12)*13 + (t % 12)] = Q3w[(size_t)i*144 + t];
    if (t < 12) {
        hw_lds[t] = log1pf(__expf(hw[t])) * 0.13608276348795434f;
        bb_lds[t] = bb[t];
    }
    if (t < 160) pT_l[480 + t] = 0;
    for (int u = t; u < 1536; u += 256) {
        int h = u % 12, c = u / 12;
        wbT_l[h*136 + c] = f2bf(Wb[c*12 + h]);
    }
    const float mask_i = mask[i];

    // accumulators
    f32x4 opA = {0,0,0,0}, opB = {0,0,0,0};
    float oacc = 0.0f;
    float o3x = 0, o3y = 0, o3z = 0;
    float dena = 0;
    const int oh = t >> 4, oc = t & 15;
    int o3h = -1, o3v = 0, o3j0 = 0, o3j1 = 32, o3slot = 0;
    if (t >= 192)    { o3h = (t - 192) >> 3;      o3v = (t - 192) & 7; }
    else if (t < 32) { o3h = 8 + (t >> 3);        o3v = t & 7;        o3j1 = 16; }
    else if (t < 64) { o3h = 8 + ((t - 32) >> 3); o3v = (t - 32) & 7; o3j0 = 16; o3slot = 1; }
    const int denh = (t >= 64 && t < 76) ? (t - 64) : -1;

    const int jj  = t >> 3, c16 = t & 7;
    const float* zbase = z + ((size_t)i*768 + chunk*384 + jj)*128 + c16*16;
    const int chS  = (jj >> 2)*8 + c16;                 // subtile 0..63
    const int chP  = chS + HOFF(chS >> 4);              // placed slot
    const int sidx = chP*88 + (jj & 3)*16;              // element index

    __syncthreads();

    for (int tile = 0; tile < 12; tile++) {
        const int j0 = chunk*384 + tile*32;

        // ---- phase A: load z tile, convert, store placed-subtile LDS ----
        {
            const float* zp = zbase + (size_t)tile * 32 * 128;
            float4 f0 = *(const float4*)(zp + 0);
            float4 f1 = *(const float4*)(zp + 4);
            float4 f2 = *(const float4*)(zp + 8);
            float4 f3 = *(const float4*)(zp + 12);
            uint4* dst = (uint4*)&z_l[sidx];
            dst[0] = uint4{pk2(f0.x,f0.y), pk2(f0.z,f0.w), pk2(f1.x,f1.y), pk2(f1.z,f1.w)};
            dst[1] = uint4{pk2(f2.x,f2.y), pk2(f2.z,f2.w), pk2(f3.x,f3.y), pk2(f3.z,f3.w)};
        }
        __syncthreads();

        // ---- phase B1: B = z@Wb via MFMA, waves 0 and 1 ----
        if (wv < 2) {
            f32x4 ab = {0,0,0,0};
            const int jt = wv;
            #pragma unroll
            for (int ks = 0; ks < 4; ks++) {
                short8 bf = *(const short8*)&wbT_l[lm*136 + ks*32 + g*8];
                int jr = jt*16 + lm;
                int ch = (jr >> 2)*8 + ks*2 + (g >> 1);
                int cp = ch + HOFF(ch >> 4);
                short8 a = *(const short8*)&z_l[cp*88 + (jr & 3)*16 + (g & 1)*8];
                ab = __builtin_amdgcn_mfma_f32_16x16x32_bf16(a, bf, ab, 0, 0, 0);
            }
            if (lm < 12) {
                #pragma unroll
                for (int r = 0; r < 4; r++)
                    p_l[(jt*16 + g*4 + r)*17 + lm] = ab[r];
            }
        }
        __syncthreads();

        // ---- phase B2: finish logits, exp, store p (f32) and p^T (bf16) ----
        // items: id=t (all threads), id=t+128 (threads 128..255 -> W2/W3,
        // which skipped B1; W0/W1 did B1).
        {
            auto b2item = [&](int pr) {
                int jjq = pr / 12;
                int h   = pr - jjq*12;
                int j   = j0 + jjq;
                float Bv = p_l[jjq*17 + h];
                const unsigned short* kp = Kw + (size_t)j*192 + h*16;
                short8 kA = *(const short8*)(kp);
                short8 kB = *(const short8*)(kp + 8);
                float qk = 0.0f;
                #pragma unroll
                for (int e = 0; e < 8; e++) qk += Q_lds[h*17 + e]     * bf2f((unsigned short)kA[e]);
                #pragma unroll
                for (int e = 0; e < 8; e++) qk += Q_lds[h*17 + 8 + e] * bf2f((unsigned short)kB[e]);
                const unsigned short* k3p = K3w + (size_t)j*144 + h*12;
                short4_t c0v = *(const short4_t*)(k3p);
                short4_t c1v = *(const short4_t*)(k3p + 4);
                short4_t c2v = *(const short4_t*)(k3p + 8);
                float d2 = 0.0f;
                #pragma unroll
                for (int e = 0; e < 4; e++) { float d = Q3_lds[h*13 + e]     - bf2f((unsigned short)c0v[e]); d2 += d*d; }
                #pragma unroll
                for (int e = 0; e < 4; e++) { float d = Q3_lds[h*13 + 4 + e] - bf2f((unsigned short)c1v[e]); d2 += d*d; }
                #pragma unroll
                for (int e = 0; e < 4; e++) { float d = Q3_lds[h*13 + 8 + e] - bf2f((unsigned short)c2v[e]); d2 += d*d; }
                float mj = mask[j];
                float lg = qk * 0.14433756729740643f
                         + (Bv + bb_lds[h]) * 0.5773502691896258f
                         - 0.5f * hw_lds[h] * d2
                         + (mask_i * mj - 1.0f) * 1e9f;
                float p = __expf(lg);
                p_l[jjq*17 + h]  = p;
                pT_l[h*40 + jjq] = f2bf(p);
            };
            b2item(t);
            if (t >= 128) b2item(t + 128);
        }
        __syncthreads();

        // ---- phase C: O_pair MFMA (conflict-free placed subtiles) ----
        {
            const int nt0 = wv*2;
            short8 ap = *(const short8*)((const char*)pT_l + lm*80 + g*16);
            short8 b0, b1;
            #pragma unroll
            for (int e = 0; e < 8; e++) {
                int jje = g*8 + e;
                int su  = (jje >> 2)*8;
                int ro  = (jje & 3)*16;
                int cp0 = su + nt0 + HOFF(g);       // (su+nt0)>>4 == g
                b0[e] = (short)z_l[cp0*88 + ro + lm];
                b1[e] = (short)z_l[(cp0 + 1)*88 + ro + lm];
            }
            opA = __builtin_amdgcn_mfma_f32_16x16x32_bf16(ap, b0, opA, 0, 0, 0);
            opB = __builtin_amdgcn_mfma_f32_16x16x32_bf16(ap, b1, opB, 0, 0, 0);
        }
        if (t < 192) {
            #pragma unroll 8
            for (int jjq = 0; jjq < 32; jjq++) {
                float p = p_l[jjq*17 + oh];
                oacc += p * bf2f(Vw[(size_t)(j0 + jjq)*192 + oh*16 + oc]);
            }
        }
        if (o3h >= 0) {
            #pragma unroll 8
            for (int jjq = o3j0; jjq < o3j1; jjq++) {
                float p = p_l[jjq*17 + o3h];
                short4_t v4 = *(const short4_t*)(V3w + (size_t)(j0 + jjq)*384 + (o3h*8 + o3v)*4);
                o3x += p * bf2f((unsigned short)v4[0]);
                o3y += p * bf2f((unsigned short)v4[1]);
                o3z += p * bf2f((unsigned short)v4[2]);
            }
        }
        if (denh >= 0) {
            #pragma unroll 8
            for (int jjq = 0; jjq < 32; jjq++) dena += p_l[jjq*17 + denh];
        }
        __syncthreads();
    }

    // ------- write partials -------
    float* pb = part3 + (size_t)blockIdx.x * 2560;
    if (t < 192) pb[t] = oacc;
    if (o3h >= 0) {
        int base = 192 + o3slot*288 + (o3h*8 + o3v)*3;
        pb[base+0] = o3x; pb[base+1] = o3y; pb[base+2] = o3z;
    }
    if (denh >= 0) pb[2304 + denh] = dena;
    {
        const int nt0 = wv*2;
        #pragma unroll
        for (int r = 0; r < 4; r++) {
            int h = g*4 + r;
            if (h < 12) {
                pb[768 + h*128 + nt0*16 + lm]       = opA[r];
                pb[768 + h*128 + (nt0 + 1)*16 + lm] = opB[r];
            }
        }
    }
}

// ---------------------------------------------------------------------------
// Kernel 3b: combine 2 j-chunks, divide by den, rotate O3, write OF row.
// ---------------------------------------------------------------------------
__global__ __launch_bounds__(256) void combine_kernel(
    const float* __restrict__ part3, const float* __restrict__ rots,
    const float* __restrict__ trans, unsigned short* __restrict__ OF)
{
    const int i = blockIdx.x;
    const int t = threadIdx.x;
    const float* pa = part3 + (size_t)i*2*2560;
    const float* pb = pa + 2560;
    __shared__ float den_s[12];
    if (t < 12) den_s[t] = pa[2304 + t] + pb[2304 + t];
    __syncthreads();

    const size_t ofb = (size_t)i * 2112;
    if (t < 192) OF[ofb + t] = f2bf((pa[t] + pb[t]) / den_s[t >> 4]);
    if (t < 96) {
        int h = t >> 3, v = t & 7;
        float den = den_s[h];
        int base = 192 + t*3;
        float m0 = pa[base+0] + pb[base+0];
        float m1 = pa[base+1] + pb[base+1];
        float m2 = pa[base+2] + pb[base+2];
        if (h >= 8) {   // slot B contributions (j 16..31 halves)
            m0 += pa[base+288+0] + pb[base+288+0];
            m1 += pa[base+288+1] + pb[base+288+1];
            m2 += pa[base+288+2] + pb[base+288+2];
        }
        m0 = m0 / den - trans[i*3+0];
        m1 = m1 / den - trans[i*3+1];
        m2 = m2 / den - trans[i*3+2];
        const float* R = rots + (size_t)i*9;
        float r0v = R[0]*m0 + R[3]*m1 + R[6]*m2;
        float r1v = R[1]*m0 + R[4]*m1 + R[7]*m2;
        float r2v = R[2]*m0 + R[5]*m1 + R[8]*m2;
        float nrm = sqrtf(r0v*r0v + r1v*r1v + r2v*r2v + 1e-20f);
        int hv = h*8 + v;
        OF[ofb + 192 + hv] = f2bf(r0v);
        OF[ofb + 288 + hv] = f2bf(r1v);
        OF[ofb + 384 + hv] = f2bf(r2v);
        OF[ofb + 480 + hv] = f2bf(nrm);
    }
    for (int u = t; u < 1536; u += 256) {
        OF[ofb + 576 + u] = f2bf((pa[768 + u] + pb[768 + u]) / den_s[u >> 7]);
    }
}

// ---------------------------------------------------------------------------
// Kernel 4a: WoT[c][k] = bf16(Wo[k][c]).  2112x384 -> 384x2112.
// ---------------------------------------------------------------------------
__global__ __launch_bounds__(256) void wot_kernel(
    const float* __restrict__ Wo, unsigned short* __restrict__ WoT)
{
    int id = blockIdx.x * 256 + threadIdx.x;   // < 101376 = 384*264
    int c  = id % 384;
    int k8 = id / 384;                          // < 264
    unsigned short tmp[8];
    #pragma unroll
    for (int e = 0; e < 8; e++)
        tmp[e] = f2bf(Wo[(size_t)(k8*8 + e)*384 + c]);
    uint4 o;
    o.x = (unsigned)tmp[0] | ((unsigned)tmp[1] << 16);
    o.y = (unsigned)tmp[2] | ((unsigned)tmp[3] << 16);
    o.z = (unsigned)tmp[4] | ((unsigned)tmp[5] << 16);
    o.w = (unsigned)tmp[6] | ((unsigned)tmp[7] << 16);
    *(uint4*)&WoT[(size_t)c*2112 + k8*8] = o;
}

// ---------------------------------------------------------------------------
// Kernel 4b: out = OF(bf16) @ WoT^T (bf16) + bo via MFMA, LDS-staged tiles.
// grid (24,3), block 256. Block: 32 rows x 128 cols; wave wv owns 32 cols.
// K-loop: 33 chunks of 64; A tile 32x64, B tile 128x64 staged coalesced.
// ---------------------------------------------------------------------------
__global__ __launch_bounds__(256) void out_gemm2(
    const unsigned short* __restrict__ OF, const unsigned short* __restrict__ WoT,
    const float* __restrict__ bo, float* __restrict__ out)
{
    __shared__ __align__(16) unsigned short aT[32 * 72];   // 4.6 KB, stride 72
    __shared__ __align__(16) unsigned short bT[128 * 72];  // 18.4 KB
    const int t = threadIdx.x;
    const int wv = t >> 6, lane = t & 63, g = lane >> 4, lm = lane & 15;
    const int i0 = blockIdx.x * 32;
    const int c0 = blockIdx.y * 128;

    f32x4 acc00 = {0,0,0,0}, acc01 = {0,0,0,0};
    f32x4 acc10 = {0,0,0,0}, acc11 = {0,0,0,0};

    const int sr = t >> 3, sc = (t & 7) * 8;   // staging: row t/8, col (t%8)*8

    for (int k0 = 0; k0 < 2112; k0 += 64) {
        __syncthreads();   // previous chunk's reads complete
        *(uint4*)&aT[sr*72 + sc] =
            *(const uint4*)&OF[(size_t)(i0 + sr)*2112 + k0 + sc];
        #pragma unroll
        for (int q = 0; q < 4; q++) {
            int br = q*32 + sr;
            *(uint4*)&bT[br*72 + sc] =
                *(const uint4*)&WoT[(size_t)(c0 + br)*2112 + k0 + sc];
        }
        __syncthreads();
        #pragma unroll
        for (int kk = 0; kk < 2; kk++) {
            short8 a0 = *(const short8*)&aT[lm*72        + kk*32 + g*8];
            short8 a1 = *(const short8*)&aT[(16+lm)*72   + kk*32 + g*8];
            short8 b0 = *(const short8*)&bT[(wv*32+lm)*72    + kk*32 + g*8];
            short8 b1 = *(const short8*)&bT[(wv*32+16+lm)*72 + kk*32 + g*8];
            acc00 = __builtin_amdgcn_mfma_f32_16x16x32_bf16(a0, b0, acc00, 0, 0, 0);
            acc01 = __builtin_amdgcn_mfma_f32_16x16x32_bf16(a0, b1, acc01, 0, 0, 0);
            acc10 = __builtin_amdgcn_mfma_f32_16x16x32_bf16(a1, b0, acc10, 0, 0, 0);
            acc11 = __builtin_amdgcn_mfma_f32_16x16x32_bf16(a1, b1, acc11, 0, 0, 0);
        }
    }

    const int colA = c0 + wv*32 + lm, colB = colA + 16;
    const float bA = bo[colA], bB = bo[colB];
    #pragma unroll
    for (int r = 0; r < 4; r++) {
        int rowA = i0 + g*4 + r;
        int rowB = rowA + 16;
        out[(size_t)rowA*384 + colA] = acc00[r] + bA;
        out[(size_t)rowA*384 + colB] = acc01[r] + bB;
        out[(size_t)rowB*384 + colA] = acc10[r] + bA;
        out[(size_t)rowB*384 + colB] = acc11[r] + bB;
    }
}

// ---------------------------------------------------------------------------
extern "C" void kernel_launch(void* const* d_in, const int* in_sizes, int n_in,
                              void* d_out, int out_size, void* d_ws, size_t ws_size,
                              hipStream_t stream) {
    const float* s     = (const float*)d_in[0];
    const float* z     = (const float*)d_in[1];
    const float* rots  = (const float*)d_in[2];
    const float* trans = (const float*)d_in[3];
    const float* mask  = (const float*)d_in[4];
    const float* Wq    = (const float*)d_in[5];
    const float* bq    = (const float*)d_in[6];
    const float* Wkv   = (const float*)d_in[7];
    const float* bkv   = (const float*)d_in[8];
    const float* Wq3   = (const float*)d_in[9];
    const float* bq3   = (const float*)d_in[10];
    const float* Wkv3  = (const float*)d_in[11];
    const float* bkv3  = (const float*)d_in[12];
    const float* Wb    = (const float*)d_in[13];
    const float* bb    = (const float*)d_in[14];
    const float* hw    = (const float*)d_in[15];
    const float* Wo    = (const float*)d_in[16];
    const float* bo    = (const float*)d_in[17];
    float* out = (float*)d_out;

    char* ws = (char*)d_ws;
    float*          Qw   = (float*)(ws + 0);                 // 589824 B
    float*          Q3w  = (float*)(ws + 589824);            // 442368 B
    unsigned short* Kw   = (unsigned short*)(ws + 1032192);  // 294912 B
    unsigned short* Vw   = (unsigned short*)(ws + 1327104);  // 294912 B
    unsigned short* K3w  = (unsigned short*)(ws + 1622016);  // 221184 B
    unsigned short* V3w  = (unsigned short*)(ws + 1843200);  // 589824 B
    float*          P3q  = (float*)(ws + 2433024);           // 442368 B
    float*          P3kv = (float*)(ws + 2875392);           // 1327104 B
    unsigned short* OF   = (unsigned short*)(ws + 4202496);  // 3244032 B
    float*          part3 = (float*)(ws + 7446528);          // 15728640 B (ends 23175168)
    unsigned short* WoT  = (unsigned short*)(ws + 23175168); // 1622016 B

    wot_kernel<<<396, 256, 0, stream>>>(Wo, WoT);
    proj_kernel<<<dim3(24, 9), 256, 0, stream>>>(
        s, Wq, bq, Wkv, bkv, Wq3, bq3, Wkv3, bkv3, Qw, Kw, Vw, P3q, P3kv);
    rot3_kernel<<<768, 192, 0, stream>>>(P3q, P3kv, rots, trans, Q3w, K3w, V3w);
    ipa_main<<<1536, 256, 0, stream>>>(
        z, mask, Wb, bb, hw, Qw, Kw, Vw, Q3w, K3w, V3w, part3);
    combine_kernel<<<768, 256, 0, stream>>>(part3, rots, trans, OF);
    out_gemm2<<<dim3(24, 3), 256, 0, stream>>>(OF, WoT, bo, out);
}